// Round 10
// baseline (301.567 us; speedup 1.0000x reference)
//
#include <hip/hip_runtime.h>

typedef _Float16 f16;
typedef __attribute__((ext_vector_type(4))) _Float16 f16x4;
typedef __attribute__((ext_vector_type(8))) _Float16 f16x8;
typedef __attribute__((ext_vector_type(4))) float f32x4;

#define NB 2
#define NS 2048
#define NHID 2048
#define N_H 16
#define N_KV 4
#define N_HD 128

__device__ __forceinline__ void gload16(void* lds, const void* g) {
  __builtin_amdgcn_global_load_lds(
      (const __attribute__((address_space(1))) unsigned int*)g,
      (__attribute__((address_space(3))) unsigned int*)lds, 16, 0, 0);
}

// ---------------- fused f32 -> f16 convert for all 5 inputs ----------------
__global__ __launch_bounds__(256) void cvt_all(
    const float* __restrict__ hs, const float* __restrict__ Wq,
    const float* __restrict__ Wk, const float* __restrict__ Wv,
    const float* __restrict__ Wo, f16* __restrict__ Xh,
    f16* __restrict__ Wqkv, f16* __restrict__ Woh) {
  int i = blockIdx.x * 256 + threadIdx.x;  // float4 index, total 4718592
  const float* src;
  f16* dst;
  int j;
  if (i < 2097152)      { src = hs; dst = Xh;             j = i; }
  else if (i < 3145728) { src = Wq; dst = Wqkv;           j = i - 2097152; }
  else if (i < 3407872) { src = Wk; dst = Wqkv + 4194304; j = i - 3145728; }
  else if (i < 3670016) { src = Wv; dst = Wqkv + 5242880; j = i - 3407872; }
  else                  { src = Wo; dst = Woh;            j = i - 3670016; }
  const float4 v = reinterpret_cast<const float4*>(src)[j];
  f16x4 o = {(f16)v.x, (f16)v.y, (f16)v.z, (f16)v.w};
  reinterpret_cast<f16x4*>(dst)[j] = o;
}

// ---------------- QKV GEMM: 256x192 x BK=64, grid 256 = 1/CU, 4-phase ----------------
// (R9, known-good) 8 waves, 2 LDS buffers 56KB. Counted vmcnt at END of each
// tile's last phase, BEFORE its closing barrier (cross-wave safe). V written
// transposed directly.
__global__ __launch_bounds__(512, 2) void gemm_qkv(
    const f16* __restrict__ A, const f16* __restrict__ Bm,
    f16* __restrict__ q_out, f16* __restrict__ k_out, f16* __restrict__ vt_out) {
  constexpr int K = 2048;
  constexpr int NT = 32;
  __shared__ f16 lds[2][28672];
  const int t = threadIdx.x;
  const int l = t & 63, w = t >> 6;
  const int g = l >> 4, l15 = l & 15;
  const int wr = w >> 2, wc = w & 3;
  const int orig = blockIdx.x;
  const int x = orig & 7, loc = orig >> 3;   // loc 0..31
  const int mb = (x & 3) * 4 + (loc & 3);
  const int nb = (x >> 2) * 8 + (loc >> 2);
  const f16* Ab = A + (size_t)(mb * 256) * K;
  const f16* Bb = Bm + (size_t)(nb * 192) * K;

  const int rr = ((t >> 5) << 3) | (t & 7);
  const int cc = (t >> 3) & 3;
  const int dstw = w * 512;
  int srcB[3];
#pragma unroll
  for (int j = 0; j < 3; ++j) {
    int db0 = j * 4096 + t * 8;
    int h = (db0 >= 6144) ? 1 : 0;
    int u = (db0 - h * 6144) >> 3;
    int rowB = ((u >> 5) << 3) | (u & 7);
    int ccB = (u >> 3) & 3;
    srcB[j] = rowB * K + h * 32 + ccB * 8;
  }

  auto stageA = [&](int tile, int j) {
    int h = j >> 1, gi = j & 1;
    gload16(&lds[tile & 1][h * 8192 + gi * 4096 + dstw],
            Ab + (size_t)(gi * 128 + rr) * K + tile * 64 + h * 32 + cc * 8);
  };
  auto stageB = [&](int tile, int j) {
    gload16(&lds[tile & 1][16384 + j * 4096 + dstw],
            Bb + (size_t)srcB[j] + tile * 64);
  };

  const int fragoff = ((l15 >> 3) << 8) + (g << 6) + ((l15 & 7) << 3);
  f32x4 acc[8][3] = {};

#pragma unroll
  for (int j = 0; j < 3; ++j) stageB(0, j);
#pragma unroll
  for (int j = 0; j < 4; ++j) stageA(0, j);
#pragma unroll
  for (int j = 0; j < 3; ++j) stageB(1, j);
  asm volatile("s_waitcnt vmcnt(3)" ::: "memory");
  __builtin_amdgcn_s_barrier();

  f16x8 bf[3][2];
  for (int T = 0; T < NT; ++T) {
    const f16* buf = lds[T & 1];
#pragma unroll
    for (int q = 0; q < 4; ++q) {
      f16x8 af[2][2];
#pragma unroll
      for (int i = 0; i < 2; ++i)
#pragma unroll
        for (int ks = 0; ks < 2; ++ks)
          af[i][ks] = *reinterpret_cast<const f16x8*>(
              buf + ks * 8192 + (wr * 128 + (2 * q + i) * 16) * 32 + fragoff);
      if (q == 0) {
#pragma unroll
        for (int ni = 0; ni < 3; ++ni)
#pragma unroll
          for (int ks = 0; ks < 2; ++ks)
            bf[ni][ks] = *reinterpret_cast<const f16x8*>(
                buf + 16384 + ks * 6144 + (wc * 48 + ni * 16) * 32 + fragoff);
      }
      if (q == 0)      { if (T + 1 < NT) { stageA(T + 1, 0); stageA(T + 1, 1); } }
      else if (q == 1) { if (T + 1 < NT) { stageA(T + 1, 2); stageA(T + 1, 3); } }
      else if (q == 2) { if (T + 2 < NT) { stageB(T + 2, 0); stageB(T + 2, 1); } }
      else             { if (T + 2 < NT) { stageB(T + 2, 2); } }
      __builtin_amdgcn_s_barrier();
      asm volatile("s_waitcnt lgkmcnt(0)" ::: "memory");
      __builtin_amdgcn_sched_barrier(0);
      __builtin_amdgcn_s_setprio(1);
#pragma unroll
      for (int i = 0; i < 2; ++i)
#pragma unroll
        for (int ni = 0; ni < 3; ++ni)
#pragma unroll
          for (int ks = 0; ks < 2; ++ks)
            acc[2 * q + i][ni] = __builtin_amdgcn_mfma_f32_16x16x32_f16(
                af[i][ks], bf[ni][ks], acc[2 * q + i][ni], 0, 0, 0);
      __builtin_amdgcn_s_setprio(0);
      if (q == 3 && T + 1 < NT) {
        if (T + 2 < NT) asm volatile("s_waitcnt vmcnt(3)" ::: "memory");
        else            asm volatile("s_waitcnt vmcnt(0)" ::: "memory");
      }
      __builtin_amdgcn_s_barrier();
    }
  }

#pragma unroll
  for (int mi = 0; mi < 8; ++mi) {
    int m0 = mb * 256 + wr * 128 + mi * 16 + 4 * g;
    int b = m0 >> 11, s0 = m0 & (NS - 1);
#pragma unroll
    for (int ni = 0; ni < 3; ++ni) {
      int n = nb * 192 + wc * 48 + ni * 16 + l15;
      if (n < 2048) {
        int h = n >> 7, d = n & 127;
        f16* qp = q_out + (((size_t)(b * N_H + h)) * NS + s0) * N_HD + d;
#pragma unroll
        for (int r = 0; r < 4; ++r) qp[r * N_HD] = (f16)acc[mi][ni][r];
      } else if (n < 2560) {
        int n2 = n - 2048, kvh = n2 >> 7, d = n2 & 127;
        f16* kp = k_out + (((size_t)(b * N_KV + kvh)) * NS + s0) * N_HD + d;
#pragma unroll
        for (int r = 0; r < 4; ++r) kp[r * N_HD] = (f16)acc[mi][ni][r];
      } else {
        int n3 = n - 2560, kvh = n3 >> 7, d = n3 & 127;
        f16x4 o4 = {(f16)acc[mi][ni][0], (f16)acc[mi][ni][1],
                    (f16)acc[mi][ni][2], (f16)acc[mi][ni][3]};
        *reinterpret_cast<f16x4*>(
            vt_out + (((size_t)(b * N_KV + kvh)) * N_HD + d) * NS + s0) = o4;
      }
    }
  }
}

// ---------------- outproj GEMM: 128x256 x BK=64, grid 256 = 1/CU, 2-phase ----------------
// (R9, known-good)
__global__ __launch_bounds__(512, 2) void gemm_out(
    const f16* __restrict__ A, const f16* __restrict__ Bm,
    float* __restrict__ f_out, const float* __restrict__ bias) {
  constexpr int K = 2048;
  constexpr int NT = 32;
  __shared__ f16 lds[2][24576];
  const int t = threadIdx.x;
  const int l = t & 63, w = t >> 6;
  const int g = l >> 4, l15 = l & 15;
  const int wr = w >> 2, wc = w & 3;
  const int orig = blockIdx.x;
  const int x = orig & 7, loc = orig >> 3;   // loc 0..31
  const int mb = (x & 3) * 8 + (loc & 7);
  const int nb = (x >> 2) * 4 + (loc >> 3);
  const f16* Ab = A + (size_t)(mb * 128) * K;
  const f16* Bb = Bm + (size_t)(nb * 256) * K;

  const int rr = ((t >> 5) << 3) | (t & 7);
  const int cc = (t >> 3) & 3;
  const int dstw = w * 512;

  auto stageA = [&](int tile, int h) {
    gload16(&lds[tile & 1][h * 4096 + dstw],
            Ab + (size_t)rr * K + tile * 64 + h * 32 + cc * 8);
  };
  auto stageB = [&](int tile, int j) {
    int h = j >> 1, gi = j & 1;
    gload16(&lds[tile & 1][8192 + h * 8192 + gi * 4096 + dstw],
            Bb + (size_t)(gi * 128 + rr) * K + tile * 64 + h * 32 + cc * 8);
  };

  const int fragoff = ((l15 >> 3) << 8) + (g << 6) + ((l15 & 7) << 3);
  f32x4 acc[4][4] = {};

  stageA(0, 0); stageA(0, 1);
#pragma unroll
  for (int j = 0; j < 4; ++j) stageB(0, j);
#pragma unroll
  for (int j = 0; j < 4; ++j) stageB(1, j);
  asm volatile("s_waitcnt vmcnt(4)" ::: "memory");
  __builtin_amdgcn_s_barrier();

  f16x8 bf[4][2];
  for (int T = 0; T < NT; ++T) {
    const f16* buf = lds[T & 1];
#pragma unroll
    for (int q = 0; q < 2; ++q) {
      f16x8 af[2][2];
#pragma unroll
      for (int i = 0; i < 2; ++i)
#pragma unroll
        for (int ks = 0; ks < 2; ++ks)
          af[i][ks] = *reinterpret_cast<const f16x8*>(
              buf + ks * 4096 + (wr * 64 + (2 * q + i) * 16) * 32 + fragoff);
      if (q == 0) {
#pragma unroll
        for (int ni = 0; ni < 4; ++ni)
#pragma unroll
          for (int ks = 0; ks < 2; ++ks)
            bf[ni][ks] = *reinterpret_cast<const f16x8*>(
                buf + 8192 + ks * 8192 + (wc * 64 + ni * 16) * 32 + fragoff);
      }
      if (q == 0) {
        if (T + 1 < NT) { stageA(T + 1, 0); stageA(T + 1, 1); }
      } else {
        if (T + 2 < NT) { stageB(T + 2, 0); stageB(T + 2, 1); stageB(T + 2, 2); stageB(T + 2, 3); }
      }
      __builtin_amdgcn_s_barrier();
      asm volatile("s_waitcnt lgkmcnt(0)" ::: "memory");
      __builtin_amdgcn_sched_barrier(0);
      __builtin_amdgcn_s_setprio(1);
#pragma unroll
      for (int i = 0; i < 2; ++i)
#pragma unroll
        for (int ni = 0; ni < 4; ++ni)
#pragma unroll
          for (int ks = 0; ks < 2; ++ks)
            acc[2 * q + i][ni] = __builtin_amdgcn_mfma_f32_16x16x32_f16(
                af[i][ks], bf[ni][ks], acc[2 * q + i][ni], 0, 0, 0);
      __builtin_amdgcn_s_setprio(0);
      if (q == 1 && T + 1 < NT) {
        if (T + 2 < NT) asm volatile("s_waitcnt vmcnt(4)" ::: "memory");
        else            asm volatile("s_waitcnt vmcnt(0)" ::: "memory");
      }
      __builtin_amdgcn_s_barrier();
    }
  }

#pragma unroll
  for (int mi = 0; mi < 4; ++mi) {
    int m0 = mb * 128 + wr * 64 + mi * 16 + 4 * g;
#pragma unroll
    for (int ni = 0; ni < 4; ++ni) {
      int n = nb * 256 + wc * 64 + ni * 16 + l15;
#pragma unroll
      for (int r = 0; r < 4; ++r)
        f_out[(size_t)(m0 + r) * NHID + n] = acc[mi][ni][r] + bias[n];
    }
  }
}

// ---------------- causal GQA flash attention (V from L2, 4 blocks/CU) ----------------
// Un-paired q-tiles, grid 1024 (all resident: 4 blocks/CU = 4 waves/SIMD).
// K double-buffered in LDS; V^T read directly from global (L2-resident under
// the XCD swizzle; loads depend only on kt -> pipeline under QK/softmax).
// LDS = 32KB K + 8KB P = 40960 B exactly -> 4 blocks/CU. Per-CU balance: the
// 4 resident blocks get qt = {c, 31-c, c, 31-c} (sum 66 units) via the
// round-j mirrored mapping, assuming breadth-first round-robin dispatch.
__device__ __forceinline__ void stage_k(const f16* __restrict__ Kp,
                                        f16* Kl, int kt, int w, int l) {
#pragma unroll
  for (int it = 0; it < 4; ++it) {
    int cb = (it * 4 + w) * 64;
    int c = cb + l;
    int krow = c >> 4, pch = c & 15;
    int sch = (pch & 8) | ((pch ^ krow) & 7);
    gload16(Kl + cb * 8, Kp + (size_t)(kt * 64 + krow) * N_HD + sch * 8);
  }
}

__device__ __forceinline__ void attn_step(
    const f16x8* qf, f32x4* oacc, float* mrow, float* lrow, int q0, int kt,
    const f16* Kl, const f16* __restrict__ Vp, f16* Pw, int g, int l15, bool diag) {
  // S = Q K^T (Q pre-scaled by log2e): acc D[q=4g+r][kpos=l15+16nt]
  f32x4 sacc[4];
#pragma unroll
  for (int nt = 0; nt < 4; ++nt) {
    f32x4 z = {0.f, 0.f, 0.f, 0.f};
#pragma unroll
    for (int ks = 0; ks < 4; ++ks) {
      int kr = nt * 16 + l15;
      int ch = ks * 4 + g;
      int sw = (ch & 8) | ((ch ^ kr) & 7);
      f16x8 kf = *reinterpret_cast<const f16x8*>(Kl + kr * 128 + sw * 8);
      z = __builtin_amdgcn_mfma_f32_16x16x32_f16(qf[ks], kf, z, 0, 0, 0);
    }
    sacc[nt] = z;
  }

  // causal mask + wave-parallel max; exp2; scale old state
  float p[4][4];
#pragma unroll
  for (int r = 0; r < 4; ++r) {
    int qg = q0 + r;
    float m = -3.0e38f;
#pragma unroll
    for (int nt = 0; nt < 4; ++nt) {
      float sv = sacc[nt][r];
      if (diag) {
        int kg = kt * 64 + nt * 16 + l15;
        if (kg > qg) sv = -3.0e38f;
      }
      p[nt][r] = sv;
      m = fmaxf(m, sv);
    }
#pragma unroll
    for (int off = 8; off >= 1; off >>= 1) m = fmaxf(m, __shfl_xor(m, off));
    float m2 = fmaxf(mrow[r], m);
    float alpha = __builtin_amdgcn_exp2f(mrow[r] - m2);
    mrow[r] = m2;
    lrow[r] *= alpha;
#pragma unroll
    for (int nt = 0; nt < 4; ++nt)
      p[nt][r] = __builtin_amdgcn_exp2f(p[nt][r] - m2);
#pragma unroll
    for (int dt = 0; dt < 8; ++dt) oacc[dt][r] *= alpha;
  }

  // P -> per-wave LDS (swizzled), then read back as A-op fragments
#pragma unroll
  for (int nt = 0; nt < 4; ++nt)
#pragma unroll
    for (int r = 0; r < 4; ++r) {
      int ql = 4 * g + r;
      int kp = nt * 16 + l15;
      int ch = kp >> 3;
      int idx = ql * 64 + (ch ^ (ql & 7)) * 8 + (kp & 7);
      Pw[idx] = (f16)p[nt][r];
    }
  asm volatile("s_waitcnt lgkmcnt(0)" ::: "memory");
  __builtin_amdgcn_sched_barrier(0);

  f16x8 pa[2];
#pragma unroll
  for (int ks2 = 0; ks2 < 2; ++ks2) {
    int ch = ks2 * 4 + g;
    pa[ks2] = *reinterpret_cast<const f16x8*>(&Pw[l15 * 64 + (ch ^ (l15 & 7)) * 8]);
  }
  // row-sum via ones-MFMA
  const f16x8 ones = {(f16)1.f, (f16)1.f, (f16)1.f, (f16)1.f,
                      (f16)1.f, (f16)1.f, (f16)1.f, (f16)1.f};
  f32x4 lacc = {0.f, 0.f, 0.f, 0.f};
#pragma unroll
  for (int ks2 = 0; ks2 < 2; ++ks2)
    lacc = __builtin_amdgcn_mfma_f32_16x16x32_f16(pa[ks2], ones, lacc, 0, 0, 0);

  // O += P V : B-op = V^T[d][k] read directly from global (L2-resident)
  const f16* vbase = Vp + (size_t)kt * 64;
#pragma unroll
  for (int dt = 0; dt < 8; ++dt) {
    const f16* vrow = vbase + (size_t)(dt * 16 + l15) * NS;
#pragma unroll
    for (int ks2 = 0; ks2 < 2; ++ks2) {
      f16x8 vf = *reinterpret_cast<const f16x8*>(vrow + ks2 * 32 + g * 8);
      oacc[dt] = __builtin_amdgcn_mfma_f32_16x16x32_f16(pa[ks2], vf, oacc[dt], 0, 0, 0);
    }
  }
#pragma unroll
  for (int r = 0; r < 4; ++r) lrow[r] += lacc[r];
}

__global__ __launch_bounds__(256, 4) void attn_kernel(
    const f16* __restrict__ Q, const f16* __restrict__ K,
    const f16* __restrict__ Vt, f16* __restrict__ O) {
  __shared__ f16 Klds[2][64 * 128];   // 32 KB
  __shared__ f16 Plds[4][16 * 64];    // 8 KB  -> total 40960 B
  const int t = threadIdx.x, l = t & 63, w = t >> 6;
  const int g = l >> 4, l15 = l & 15;
  // grid 1024: XCD x owns (b,kvh) group x; loc = round j (0..3) x CU c (0..31)
  const int orig = blockIdx.x;
  const int x = orig & 7, loc = orig >> 3;   // loc 0..127
  const int b = x >> 2, kvh = x & 3;
  const int jj = loc >> 5, c = loc & 31;
  const int h = kvh * 4 + jj;
  const int qt = (jj & 1) ? (31 - c) : c;
  const f16* Qp = Q + ((size_t)(b * N_H + h)) * NS * N_HD;
  const f16* Kp = K + ((size_t)(b * N_KV + kvh)) * NS * N_HD;
  const f16* Vp = Vt + ((size_t)(b * N_KV + kvh)) * N_HD * NS;

  const f16 l2e = (f16)1.44269504f;
  f16x8 qf[4];
  const int qr = qt * 64 + w * 16 + l15;
#pragma unroll
  for (int ks = 0; ks < 4; ++ks) {
    qf[ks] = *reinterpret_cast<const f16x8*>(Qp + (size_t)qr * N_HD + ks * 32 + g * 8);
#pragma unroll
    for (int j = 0; j < 8; ++j) qf[ks][j] *= l2e;
  }

  f32x4 o[8] = {};
  float m[4], lr[4];
#pragma unroll
  for (int r = 0; r < 4; ++r) { m[r] = -3.0e38f; lr[r] = 0.f; }
  const int q0 = qt * 64 + w * 16 + 4 * g;

  stage_k(Kp, Klds[0], 0, w, l);
  asm volatile("s_waitcnt vmcnt(0)" ::: "memory");
  __syncthreads();
  int cur = 0;
  for (int kt = 0; kt <= qt; ++kt) {
    if (kt < qt)
      stage_k(Kp, Klds[cur ^ 1], kt + 1, w, l);
    attn_step(qf, o, m, lr, q0, kt, Klds[cur], Vp, Plds[w], g, l15, kt == qt);
    asm volatile("s_waitcnt vmcnt(0)" ::: "memory");
    __syncthreads();
    cur ^= 1;
  }

  // normalize + write attn_out [B*S][NH*HD] fp16
#pragma unroll
  for (int r = 0; r < 4; ++r) {
    float inv = 1.0f / lr[r];
    f16* orow = O + (size_t)(b * NS + q0 + r) * NHID + h * N_HD;
#pragma unroll
    for (int dt = 0; dt < 8; ++dt) orow[dt * 16 + l15] = (f16)(o[dt][r] * inv);
  }
}

extern "C" void kernel_launch(void* const* d_in, const int* in_sizes, int n_in,
                              void* d_out, int out_size, void* d_ws, size_t ws_size,
                              hipStream_t stream) {
  const float* hs = (const float*)d_in[0];
  const float* Wq = (const float*)d_in[1];
  const float* Wk = (const float*)d_in[2];
  const float* Wv = (const float*)d_in[3];
  const float* Wo = (const float*)d_in[4];
  const float* bo = (const float*)d_in[5];
  float* out = (float*)d_out;

  char* ws = (char*)d_ws;
  f16* Xh   = (f16*)(ws);
  f16* Wqkv = (f16*)(ws + 16777216);
  f16* Woh  = (f16*)(ws + 29360128);
  f16* Qb   = (f16*)(ws + 37748736);
  f16* Kb   = (f16*)(ws + 54525952);
  f16* Vtb  = (f16*)(ws + 62914560);
  f16* Ob   = Xh;  // X dead after QKV GEMM; reuse for attention output

  cvt_all<<<18432, 256, 0, stream>>>(hs, Wq, Wk, Wv, Wo, Xh, Wqkv, Woh);
  gemm_qkv<<<256, 512, 0, stream>>>(Xh, Wqkv, Qb, Kb, Vtb);
  attn_kernel<<<1024, 256, 0, stream>>>(Qb, Kb, Vtb, Ob);
  gemm_out<<<256, 512, 0, stream>>>(Ob, Woh, out, bo);
}

// Round 11
// 219.649 us; speedup vs baseline: 1.3729x; 1.3729x over previous
//
#include <hip/hip_runtime.h>

typedef _Float16 f16;
typedef __attribute__((ext_vector_type(4))) _Float16 f16x4;
typedef __attribute__((ext_vector_type(8))) _Float16 f16x8;
typedef __attribute__((ext_vector_type(4))) float f32x4;

#define NB 2
#define NS 2048
#define NHID 2048
#define N_H 16
#define N_KV 4
#define N_HD 128

__device__ __forceinline__ void gload16(void* lds, const void* g) {
  __builtin_amdgcn_global_load_lds(
      (const __attribute__((address_space(1))) unsigned int*)g,
      (__attribute__((address_space(3))) unsigned int*)lds, 16, 0, 0);
}

// ---------------- fused f32 -> f16 convert for all 5 inputs ----------------
__global__ __launch_bounds__(256) void cvt_all(
    const float* __restrict__ hs, const float* __restrict__ Wq,
    const float* __restrict__ Wk, const float* __restrict__ Wv,
    const float* __restrict__ Wo, f16* __restrict__ Xh,
    f16* __restrict__ Wqkv, f16* __restrict__ Woh) {
  int i = blockIdx.x * 256 + threadIdx.x;  // float4 index, total 4718592
  const float* src;
  f16* dst;
  int j;
  if (i < 2097152)      { src = hs; dst = Xh;             j = i; }
  else if (i < 3145728) { src = Wq; dst = Wqkv;           j = i - 2097152; }
  else if (i < 3407872) { src = Wk; dst = Wqkv + 4194304; j = i - 3145728; }
  else if (i < 3670016) { src = Wv; dst = Wqkv + 5242880; j = i - 3407872; }
  else                  { src = Wo; dst = Woh;            j = i - 3670016; }
  const float4 v = reinterpret_cast<const float4*>(src)[j];
  f16x4 o = {(f16)v.x, (f16)v.y, (f16)v.z, (f16)v.w};
  reinterpret_cast<f16x4*>(dst)[j] = o;
}

// ---------------- QKV GEMM: 256x192 x BK=64, grid 256 = 1/CU, 4-phase ----------------
// (R9, known-good) Counted vmcnt at END of each tile's last phase, BEFORE its
// closing barrier (cross-wave safe). V written transposed directly.
__global__ __launch_bounds__(512, 2) void gemm_qkv(
    const f16* __restrict__ A, const f16* __restrict__ Bm,
    f16* __restrict__ q_out, f16* __restrict__ k_out, f16* __restrict__ vt_out) {
  constexpr int K = 2048;
  constexpr int NT = 32;
  __shared__ f16 lds[2][28672];
  const int t = threadIdx.x;
  const int l = t & 63, w = t >> 6;
  const int g = l >> 4, l15 = l & 15;
  const int wr = w >> 2, wc = w & 3;
  const int orig = blockIdx.x;
  const int x = orig & 7, loc = orig >> 3;   // loc 0..31
  const int mb = (x & 3) * 4 + (loc & 3);
  const int nb = (x >> 2) * 8 + (loc >> 2);
  const f16* Ab = A + (size_t)(mb * 256) * K;
  const f16* Bb = Bm + (size_t)(nb * 192) * K;

  const int rr = ((t >> 5) << 3) | (t & 7);
  const int cc = (t >> 3) & 3;
  const int dstw = w * 512;
  int srcB[3];
#pragma unroll
  for (int j = 0; j < 3; ++j) {
    int db0 = j * 4096 + t * 8;
    int h = (db0 >= 6144) ? 1 : 0;
    int u = (db0 - h * 6144) >> 3;
    int rowB = ((u >> 5) << 3) | (u & 7);
    int ccB = (u >> 3) & 3;
    srcB[j] = rowB * K + h * 32 + ccB * 8;
  }

  auto stageA = [&](int tile, int j) {
    int h = j >> 1, gi = j & 1;
    gload16(&lds[tile & 1][h * 8192 + gi * 4096 + dstw],
            Ab + (size_t)(gi * 128 + rr) * K + tile * 64 + h * 32 + cc * 8);
  };
  auto stageB = [&](int tile, int j) {
    gload16(&lds[tile & 1][16384 + j * 4096 + dstw],
            Bb + (size_t)srcB[j] + tile * 64);
  };

  const int fragoff = ((l15 >> 3) << 8) + (g << 6) + ((l15 & 7) << 3);
  f32x4 acc[8][3] = {};

#pragma unroll
  for (int j = 0; j < 3; ++j) stageB(0, j);
#pragma unroll
  for (int j = 0; j < 4; ++j) stageA(0, j);
#pragma unroll
  for (int j = 0; j < 3; ++j) stageB(1, j);
  asm volatile("s_waitcnt vmcnt(3)" ::: "memory");
  __builtin_amdgcn_s_barrier();

  f16x8 bf[3][2];
  for (int T = 0; T < NT; ++T) {
    const f16* buf = lds[T & 1];
#pragma unroll
    for (int q = 0; q < 4; ++q) {
      f16x8 af[2][2];
#pragma unroll
      for (int i = 0; i < 2; ++i)
#pragma unroll
        for (int ks = 0; ks < 2; ++ks)
          af[i][ks] = *reinterpret_cast<const f16x8*>(
              buf + ks * 8192 + (wr * 128 + (2 * q + i) * 16) * 32 + fragoff);
      if (q == 0) {
#pragma unroll
        for (int ni = 0; ni < 3; ++ni)
#pragma unroll
          for (int ks = 0; ks < 2; ++ks)
            bf[ni][ks] = *reinterpret_cast<const f16x8*>(
                buf + 16384 + ks * 6144 + (wc * 48 + ni * 16) * 32 + fragoff);
      }
      if (q == 0)      { if (T + 1 < NT) { stageA(T + 1, 0); stageA(T + 1, 1); } }
      else if (q == 1) { if (T + 1 < NT) { stageA(T + 1, 2); stageA(T + 1, 3); } }
      else if (q == 2) { if (T + 2 < NT) { stageB(T + 2, 0); stageB(T + 2, 1); } }
      else             { if (T + 2 < NT) { stageB(T + 2, 2); } }
      __builtin_amdgcn_s_barrier();
      asm volatile("s_waitcnt lgkmcnt(0)" ::: "memory");
      __builtin_amdgcn_sched_barrier(0);
      __builtin_amdgcn_s_setprio(1);
#pragma unroll
      for (int i = 0; i < 2; ++i)
#pragma unroll
        for (int ni = 0; ni < 3; ++ni)
#pragma unroll
          for (int ks = 0; ks < 2; ++ks)
            acc[2 * q + i][ni] = __builtin_amdgcn_mfma_f32_16x16x32_f16(
                af[i][ks], bf[ni][ks], acc[2 * q + i][ni], 0, 0, 0);
      __builtin_amdgcn_s_setprio(0);
      if (q == 3 && T + 1 < NT) {
        if (T + 2 < NT) asm volatile("s_waitcnt vmcnt(3)" ::: "memory");
        else            asm volatile("s_waitcnt vmcnt(0)" ::: "memory");
      }
      __builtin_amdgcn_s_barrier();
    }
  }

#pragma unroll
  for (int mi = 0; mi < 8; ++mi) {
    int m0 = mb * 256 + wr * 128 + mi * 16 + 4 * g;
    int b = m0 >> 11, s0 = m0 & (NS - 1);
#pragma unroll
    for (int ni = 0; ni < 3; ++ni) {
      int n = nb * 192 + wc * 48 + ni * 16 + l15;
      if (n < 2048) {
        int h = n >> 7, d = n & 127;
        f16* qp = q_out + (((size_t)(b * N_H + h)) * NS + s0) * N_HD + d;
#pragma unroll
        for (int r = 0; r < 4; ++r) qp[r * N_HD] = (f16)acc[mi][ni][r];
      } else if (n < 2560) {
        int n2 = n - 2048, kvh = n2 >> 7, d = n2 & 127;
        f16* kp = k_out + (((size_t)(b * N_KV + kvh)) * NS + s0) * N_HD + d;
#pragma unroll
        for (int r = 0; r < 4; ++r) kp[r * N_HD] = (f16)acc[mi][ni][r];
      } else {
        int n3 = n - 2560, kvh = n3 >> 7, d = n3 & 127;
        f16x4 o4 = {(f16)acc[mi][ni][0], (f16)acc[mi][ni][1],
                    (f16)acc[mi][ni][2], (f16)acc[mi][ni][3]};
        *reinterpret_cast<f16x4*>(
            vt_out + (((size_t)(b * N_KV + kvh)) * N_HD + d) * NS + s0) = o4;
      }
    }
  }
}

// ---------------- outproj GEMM: 128x256 x BK=64, grid 256 = 1/CU, 2-phase ----------------
// (R9, known-good)
__global__ __launch_bounds__(512, 2) void gemm_out(
    const f16* __restrict__ A, const f16* __restrict__ Bm,
    float* __restrict__ f_out, const float* __restrict__ bias) {
  constexpr int K = 2048;
  constexpr int NT = 32;
  __shared__ f16 lds[2][24576];
  const int t = threadIdx.x;
  const int l = t & 63, w = t >> 6;
  const int g = l >> 4, l15 = l & 15;
  const int wr = w >> 2, wc = w & 3;
  const int orig = blockIdx.x;
  const int x = orig & 7, loc = orig >> 3;   // loc 0..31
  const int mb = (x & 3) * 8 + (loc & 7);
  const int nb = (x >> 2) * 4 + (loc >> 3);
  const f16* Ab = A + (size_t)(mb * 128) * K;
  const f16* Bb = Bm + (size_t)(nb * 256) * K;

  const int rr = ((t >> 5) << 3) | (t & 7);
  const int cc = (t >> 3) & 3;
  const int dstw = w * 512;

  auto stageA = [&](int tile, int h) {
    gload16(&lds[tile & 1][h * 4096 + dstw],
            Ab + (size_t)rr * K + tile * 64 + h * 32 + cc * 8);
  };
  auto stageB = [&](int tile, int j) {
    int h = j >> 1, gi = j & 1;
    gload16(&lds[tile & 1][8192 + h * 8192 + gi * 4096 + dstw],
            Bb + (size_t)(gi * 128 + rr) * K + tile * 64 + h * 32 + cc * 8);
  };

  const int fragoff = ((l15 >> 3) << 8) + (g << 6) + ((l15 & 7) << 3);
  f32x4 acc[4][4] = {};

  stageA(0, 0); stageA(0, 1);
#pragma unroll
  for (int j = 0; j < 4; ++j) stageB(0, j);
#pragma unroll
  for (int j = 0; j < 4; ++j) stageB(1, j);
  asm volatile("s_waitcnt vmcnt(4)" ::: "memory");
  __builtin_amdgcn_s_barrier();

  f16x8 bf[4][2];
  for (int T = 0; T < NT; ++T) {
    const f16* buf = lds[T & 1];
#pragma unroll
    for (int q = 0; q < 2; ++q) {
      f16x8 af[2][2];
#pragma unroll
      for (int i = 0; i < 2; ++i)
#pragma unroll
        for (int ks = 0; ks < 2; ++ks)
          af[i][ks] = *reinterpret_cast<const f16x8*>(
              buf + ks * 4096 + (wr * 64 + (2 * q + i) * 16) * 32 + fragoff);
      if (q == 0) {
#pragma unroll
        for (int ni = 0; ni < 4; ++ni)
#pragma unroll
          for (int ks = 0; ks < 2; ++ks)
            bf[ni][ks] = *reinterpret_cast<const f16x8*>(
                buf + 8192 + ks * 8192 + (wc * 64 + ni * 16) * 32 + fragoff);
      }
      if (q == 0) {
        if (T + 1 < NT) { stageA(T + 1, 0); stageA(T + 1, 1); }
      } else {
        if (T + 2 < NT) { stageB(T + 2, 0); stageB(T + 2, 1); stageB(T + 2, 2); stageB(T + 2, 3); }
      }
      __builtin_amdgcn_s_barrier();
      asm volatile("s_waitcnt lgkmcnt(0)" ::: "memory");
      __builtin_amdgcn_sched_barrier(0);
      __builtin_amdgcn_s_setprio(1);
#pragma unroll
      for (int i = 0; i < 2; ++i)
#pragma unroll
        for (int ni = 0; ni < 4; ++ni)
#pragma unroll
          for (int ks = 0; ks < 2; ++ks)
            acc[2 * q + i][ni] = __builtin_amdgcn_mfma_f32_16x16x32_f16(
                af[i][ks], bf[ni][ks], acc[2 * q + i][ni], 0, 0, 0);
      __builtin_amdgcn_s_setprio(0);
      if (q == 1 && T + 1 < NT) {
        if (T + 2 < NT) asm volatile("s_waitcnt vmcnt(4)" ::: "memory");
        else            asm volatile("s_waitcnt vmcnt(0)" ::: "memory");
      }
      __builtin_amdgcn_s_barrier();
    }
  }

#pragma unroll
  for (int mi = 0; mi < 4; ++mi) {
    int m0 = mb * 128 + wr * 64 + mi * 16 + 4 * g;
#pragma unroll
    for (int ni = 0; ni < 4; ++ni) {
      int n = nb * 256 + wc * 64 + ni * 16 + l15;
#pragma unroll
      for (int r = 0; r < 4; ++r)
        f_out[(size_t)(m0 + r) * NHID + n] = acc[mi][ni][r] + bias[n];
    }
  }
}

// ---------------- causal GQA flash attention (8-wave paired, 4 waves/SIMD) ----------------
// 512-thread blocks: waves 0-3 own tile A (qt=pi), waves 4-7 own tile B
// (qt=31-pi) -- the two previously-serial attn_steps now run in PARALLEL
// waves. K and V double-buffered in LDS (R5 data path, attn_step verbatim).
// LDS = 32K K + 32K V + 16K P = 81920 B = exactly 2 blocks/CU -> 4 waves/SIMD.
// pi mapping: pi(loc)+pi(loc+32) = 15 so co-resident blocks sum to uniform
// duration under round-robin dispatch.
__device__ __forceinline__ void stage_kv8(const f16* __restrict__ Kp,
                                          const f16* __restrict__ Vp,
                                          f16* Kl, f16* Vl, int kt, int w, int l) {
#pragma unroll
  for (int it = 0; it < 2; ++it) {
    int cb = (it * 8 + w) * 64;
    int c = cb + l;
    int krow = c >> 4, pch = c & 15;
    int sch = (pch & 8) | ((pch ^ krow) & 7);
    gload16(Kl + cb * 8, Kp + (size_t)(kt * 64 + krow) * N_HD + sch * 8);
  }
#pragma unroll
  for (int it = 0; it < 2; ++it) {
    int cb = (it * 8 + w) * 64;
    int c = cb + l;
    int drow = c >> 3, pch = c & 7;
    int sch = (pch ^ drow) & 7;
    gload16(Vl + cb * 8, Vp + (size_t)drow * NS + kt * 64 + sch * 8);
  }
}

__device__ __forceinline__ void attn_step(
    const f16x8* qf, f32x4* oacc, float* mrow, float* lrow, int q0, int kt,
    const f16* Kl, const f16* Vl, f16* Pw, int g, int l15, bool diag) {
  // S = Q K^T (Q pre-scaled by log2e): acc D[q=4g+r][kpos=l15+16nt]
  f32x4 sacc[4];
#pragma unroll
  for (int nt = 0; nt < 4; ++nt) {
    f32x4 z = {0.f, 0.f, 0.f, 0.f};
#pragma unroll
    for (int ks = 0; ks < 4; ++ks) {
      int kr = nt * 16 + l15;
      int ch = ks * 4 + g;
      int sw = (ch & 8) | ((ch ^ kr) & 7);
      f16x8 kf = *reinterpret_cast<const f16x8*>(Kl + kr * 128 + sw * 8);
      z = __builtin_amdgcn_mfma_f32_16x16x32_f16(qf[ks], kf, z, 0, 0, 0);
    }
    sacc[nt] = z;
  }

  // causal mask + wave-parallel max; exp2; scale old state
  float p[4][4];
#pragma unroll
  for (int r = 0; r < 4; ++r) {
    int qg = q0 + r;
    float m = -3.0e38f;
#pragma unroll
    for (int nt = 0; nt < 4; ++nt) {
      float sv = sacc[nt][r];
      if (diag) {
        int kg = kt * 64 + nt * 16 + l15;
        if (kg > qg) sv = -3.0e38f;
      }
      p[nt][r] = sv;
      m = fmaxf(m, sv);
    }
#pragma unroll
    for (int off = 8; off >= 1; off >>= 1) m = fmaxf(m, __shfl_xor(m, off));
    float m2 = fmaxf(mrow[r], m);
    float alpha = __builtin_amdgcn_exp2f(mrow[r] - m2);
    mrow[r] = m2;
    lrow[r] *= alpha;
#pragma unroll
    for (int nt = 0; nt < 4; ++nt)
      p[nt][r] = __builtin_amdgcn_exp2f(p[nt][r] - m2);
#pragma unroll
    for (int dt = 0; dt < 8; ++dt) oacc[dt][r] *= alpha;
  }

  // P -> per-wave LDS (swizzled), then read back as A-op fragments
#pragma unroll
  for (int nt = 0; nt < 4; ++nt)
#pragma unroll
    for (int r = 0; r < 4; ++r) {
      int ql = 4 * g + r;
      int kp = nt * 16 + l15;
      int ch = kp >> 3;
      int idx = ql * 64 + (ch ^ (ql & 7)) * 8 + (kp & 7);
      Pw[idx] = (f16)p[nt][r];
    }
  asm volatile("s_waitcnt lgkmcnt(0)" ::: "memory");
  __builtin_amdgcn_sched_barrier(0);

  f16x8 pa[2];
#pragma unroll
  for (int ks2 = 0; ks2 < 2; ++ks2) {
    int ch = ks2 * 4 + g;
    pa[ks2] = *reinterpret_cast<const f16x8*>(&Pw[l15 * 64 + (ch ^ (l15 & 7)) * 8]);
  }
  // row-sum via ones-MFMA (all lanes get Sum_k P[row,k] in lacc[r])
  const f16x8 ones = {(f16)1.f, (f16)1.f, (f16)1.f, (f16)1.f,
                      (f16)1.f, (f16)1.f, (f16)1.f, (f16)1.f};
  f32x4 lacc = {0.f, 0.f, 0.f, 0.f};
#pragma unroll
  for (int ks2 = 0; ks2 < 2; ++ks2)
    lacc = __builtin_amdgcn_mfma_f32_16x16x32_f16(pa[ks2], ones, lacc, 0, 0, 0);
  // O += P V : B-op = V[k][d] from Vl[d][k]
#pragma unroll
  for (int dt = 0; dt < 8; ++dt)
#pragma unroll
    for (int ks2 = 0; ks2 < 2; ++ks2) {
      int d = dt * 16 + l15;
      int ch = ks2 * 4 + g;
      f16x8 vf = *reinterpret_cast<const f16x8*>(Vl + d * 64 + (ch ^ (d & 7)) * 8);
      oacc[dt] = __builtin_amdgcn_mfma_f32_16x16x32_f16(pa[ks2], vf, oacc[dt], 0, 0, 0);
    }
#pragma unroll
  for (int r = 0; r < 4; ++r) lrow[r] += lacc[r];
}

__global__ __launch_bounds__(512, 4) void attn_kernel(
    const f16* __restrict__ Q, const f16* __restrict__ K,
    const f16* __restrict__ Vt, f16* __restrict__ O) {
  __shared__ f16 Klds[2][64 * 128];   // 32 KB
  __shared__ f16 Vlds[2][128 * 64];   // 32 KB
  __shared__ f16 Plds[8][16 * 64];    // 16 KB -> 81920 B total
  const int t = threadIdx.x, l = t & 63, w = t >> 6;  // w 0..7
  const int g = l >> 4, l15 = l & 15;
  const int ws = w & 3, tile = w >> 2;  // tile 0 = A, 1 = B
  // XCD swizzle: XCD x owns (b,kvh); loc 0..63 -> (pi, h) with
  // pi(loc)+pi(loc+32)=15 for uniform co-resident duration.
  const int orig = blockIdx.x;               // 0..511
  const int x = orig & 7, loc = orig >> 3;
  const int b = x >> 2, kvh = x & 3;
  const int s = loc >> 5, u = (loc >> 4) & 1, low = loc & 15;
  const int pi = s ? (15 - low) : low;
  const int h = kvh * 4 + u + 2 * s;
  const int qtA = pi, qtB = 31 - pi;
  const int qt = tile ? qtB : qtA;
  const f16* Qp = Q + ((size_t)(b * N_H + h)) * NS * N_HD;
  const f16* Kp = K + ((size_t)(b * N_KV + kvh)) * NS * N_HD;
  const f16* Vp = Vt + ((size_t)(b * N_KV + kvh)) * N_HD * NS;

  const f16 l2e = (f16)1.44269504f;
  f16x8 qf[4];
  const int qr = qt * 64 + ws * 16 + l15;
#pragma unroll
  for (int ks = 0; ks < 4; ++ks) {
    qf[ks] = *reinterpret_cast<const f16x8*>(Qp + (size_t)qr * N_HD + ks * 32 + g * 8);
#pragma unroll
    for (int j = 0; j < 8; ++j) qf[ks][j] *= l2e;
  }

  f32x4 o[8] = {};
  float m[4], lr[4];
#pragma unroll
  for (int r = 0; r < 4; ++r) { m[r] = -3.0e38f; lr[r] = 0.f; }
  const int q0 = qt * 64 + ws * 16 + 4 * g;

  const int nkt = qtB + 1;
  stage_kv8(Kp, Vp, Klds[0], Vlds[0], 0, w, l);
  asm volatile("s_waitcnt vmcnt(0)" ::: "memory");
  __syncthreads();
  int cur = 0;
  for (int kt = 0; kt < nkt; ++kt) {
    if (kt + 1 < nkt)
      stage_kv8(Kp, Vp, Klds[cur ^ 1], Vlds[cur ^ 1], kt + 1, w, l);
    if (tile == 1 || kt <= qtA)  // wave-uniform
      attn_step(qf, o, m, lr, q0, kt, Klds[cur], Vlds[cur], Plds[w], g, l15, kt == qt);
    asm volatile("s_waitcnt vmcnt(0)" ::: "memory");
    __syncthreads();
    cur ^= 1;
  }

  // normalize + write attn_out [B*S][NH*HD] fp16
#pragma unroll
  for (int r = 0; r < 4; ++r) {
    float inv = 1.0f / lr[r];
    f16* orow = O + (size_t)(b * NS + q0 + r) * NHID + h * N_HD;
#pragma unroll
    for (int dt = 0; dt < 8; ++dt) orow[dt * 16 + l15] = (f16)(o[dt][r] * inv);
  }
}

extern "C" void kernel_launch(void* const* d_in, const int* in_sizes, int n_in,
                              void* d_out, int out_size, void* d_ws, size_t ws_size,
                              hipStream_t stream) {
  const float* hs = (const float*)d_in[0];
  const float* Wq = (const float*)d_in[1];
  const float* Wk = (const float*)d_in[2];
  const float* Wv = (const float*)d_in[3];
  const float* Wo = (const float*)d_in[4];
  const float* bo = (const float*)d_in[5];
  float* out = (float*)d_out;

  char* ws = (char*)d_ws;
  f16* Xh   = (f16*)(ws);
  f16* Wqkv = (f16*)(ws + 16777216);
  f16* Woh  = (f16*)(ws + 29360128);
  f16* Qb   = (f16*)(ws + 37748736);
  f16* Kb   = (f16*)(ws + 54525952);
  f16* Vtb  = (f16*)(ws + 62914560);
  f16* Ob   = Xh;  // X dead after QKV GEMM; reuse for attention output

  cvt_all<<<18432, 256, 0, stream>>>(hs, Wq, Wk, Wv, Wo, Xh, Wqkv, Woh);
  gemm_qkv<<<256, 512, 0, stream>>>(Xh, Wqkv, Qb, Kb, Vtb);
  attn_kernel<<<512, 512, 0, stream>>>(Qb, Kb, Vtb, Ob);
  gemm_out<<<256, 512, 0, stream>>>(Ob, Woh, out, bo);
}

// Round 12
// 203.712 us; speedup vs baseline: 1.4804x; 1.0782x over previous
//
#include <hip/hip_runtime.h>

typedef _Float16 f16;
typedef __attribute__((ext_vector_type(4))) _Float16 f16x4;
typedef __attribute__((ext_vector_type(8))) _Float16 f16x8;
typedef __attribute__((ext_vector_type(4))) float f32x4;

#define NB 2
#define NS 2048
#define NHID 2048
#define N_H 16
#define N_KV 4
#define N_HD 128

__device__ __forceinline__ void gload16(void* lds, const void* g) {
  __builtin_amdgcn_global_load_lds(
      (const __attribute__((address_space(1))) unsigned int*)g,
      (__attribute__((address_space(3))) unsigned int*)lds, 16, 0, 0);
}

// ---------------- fused f32 -> f16 convert for all 5 inputs ----------------
__global__ __launch_bounds__(256) void cvt_all(
    const float* __restrict__ hs, const float* __restrict__ Wq,
    const float* __restrict__ Wk, const float* __restrict__ Wv,
    const float* __restrict__ Wo, f16* __restrict__ Xh,
    f16* __restrict__ Wqkv, f16* __restrict__ Woh) {
  int i = blockIdx.x * 256 + threadIdx.x;  // float4 index, total 4718592
  const float* src;
  f16* dst;
  int j;
  if (i < 2097152)      { src = hs; dst = Xh;             j = i; }
  else if (i < 3145728) { src = Wq; dst = Wqkv;           j = i - 2097152; }
  else if (i < 3407872) { src = Wk; dst = Wqkv + 4194304; j = i - 3145728; }
  else if (i < 3670016) { src = Wv; dst = Wqkv + 5242880; j = i - 3407872; }
  else                  { src = Wo; dst = Woh;            j = i - 3670016; }
  const float4 v = reinterpret_cast<const float4*>(src)[j];
  f16x4 o = {(f16)v.x, (f16)v.y, (f16)v.z, (f16)v.w};
  reinterpret_cast<f16x4*>(dst)[j] = o;
}

// ---------------- QKV GEMM: 256x192 x BK=64, grid 256 = 1/CU, 4-phase ----------------
// 8 waves (2M x 4N; wave 128x48). 2 LDS buffers 56KB each. Per tile: 7 uniform
// 8KB granules (B=3, A=4). Counted vmcnt at END of each tile's last phase,
// BEFORE its closing barrier (cross-wave safe: every wave drains its loads for
// tile T+1 before the rendezvous that tile T+1's ds_reads follow).
// V written transposed directly.
__global__ __launch_bounds__(512, 2) void gemm_qkv(
    const f16* __restrict__ A, const f16* __restrict__ Bm,
    f16* __restrict__ q_out, f16* __restrict__ k_out, f16* __restrict__ vt_out) {
  constexpr int K = 2048;
  constexpr int NT = 32;
  __shared__ f16 lds[2][28672];
  const int t = threadIdx.x;
  const int l = t & 63, w = t >> 6;
  const int g = l >> 4, l15 = l & 15;
  const int wr = w >> 2, wc = w & 3;
  // XCD-rectangle swizzle over 16mb x 16nb
  const int orig = blockIdx.x;
  const int x = orig & 7, loc = orig >> 3;   // loc 0..31
  const int mb = (x & 3) * 4 + (loc & 3);
  const int nb = (x >> 2) * 8 + (loc >> 2);
  const f16* Ab = A + (size_t)(mb * 256) * K;
  const f16* Bb = Bm + (size_t)(nb * 192) * K;

  const int rr = ((t >> 5) << 3) | (t & 7);
  const int cc = (t >> 3) & 3;
  const int dstw = w * 512;
  // B granule j: invert the slot permutation for the 2x6144-f16 B region
  int srcB[3];
#pragma unroll
  for (int j = 0; j < 3; ++j) {
    int db0 = j * 4096 + t * 8;
    int h = (db0 >= 6144) ? 1 : 0;
    int u = (db0 - h * 6144) >> 3;
    int rowB = ((u >> 5) << 3) | (u & 7);
    int ccB = (u >> 3) & 3;
    srcB[j] = rowB * K + h * 32 + ccB * 8;
  }

  auto stageA = [&](int tile, int j) {  // j: h=j>>1, gi=j&1
    int h = j >> 1, gi = j & 1;
    gload16(&lds[tile & 1][h * 8192 + gi * 4096 + dstw],
            Ab + (size_t)(gi * 128 + rr) * K + tile * 64 + h * 32 + cc * 8);
  };
  auto stageB = [&](int tile, int j) {
    gload16(&lds[tile & 1][16384 + j * 4096 + dstw],
            Bb + (size_t)srcB[j] + tile * 64);
  };

  const int fragoff = ((l15 >> 3) << 8) + (g << 6) + ((l15 & 7) << 3);
  f32x4 acc[8][3] = {};

  // prologue: tile0 complete + tile1 B; drain all but tile1's 3 B, then barrier
#pragma unroll
  for (int j = 0; j < 3; ++j) stageB(0, j);
#pragma unroll
  for (int j = 0; j < 4; ++j) stageA(0, j);
#pragma unroll
  for (int j = 0; j < 3; ++j) stageB(1, j);
  asm volatile("s_waitcnt vmcnt(3)" ::: "memory");
  __builtin_amdgcn_s_barrier();

  f16x8 bf[3][2];
  for (int T = 0; T < NT; ++T) {
    const f16* buf = lds[T & 1];
#pragma unroll
    for (int q = 0; q < 4; ++q) {
      f16x8 af[2][2];
#pragma unroll
      for (int i = 0; i < 2; ++i)
#pragma unroll
        for (int ks = 0; ks < 2; ++ks)
          af[i][ks] = *reinterpret_cast<const f16x8*>(
              buf + ks * 8192 + (wr * 128 + (2 * q + i) * 16) * 32 + fragoff);
      if (q == 0) {
#pragma unroll
        for (int ni = 0; ni < 3; ++ni)
#pragma unroll
          for (int ks = 0; ks < 2; ++ks)
            bf[ni][ks] = *reinterpret_cast<const f16x8*>(
                buf + 16384 + ks * 6144 + (wc * 48 + ni * 16) * 32 + fragoff);
      }
      if (q == 0)      { if (T + 1 < NT) { stageA(T + 1, 0); stageA(T + 1, 1); } }
      else if (q == 1) { if (T + 1 < NT) { stageA(T + 1, 2); stageA(T + 1, 3); } }
      else if (q == 2) { if (T + 2 < NT) { stageB(T + 2, 0); stageB(T + 2, 1); } }
      else             { if (T + 2 < NT) { stageB(T + 2, 2); } }
      __builtin_amdgcn_s_barrier();
      asm volatile("s_waitcnt lgkmcnt(0)" ::: "memory");
      __builtin_amdgcn_sched_barrier(0);
      __builtin_amdgcn_s_setprio(1);
#pragma unroll
      for (int i = 0; i < 2; ++i)
#pragma unroll
        for (int ni = 0; ni < 3; ++ni)
#pragma unroll
          for (int ks = 0; ks < 2; ++ks)
            acc[2 * q + i][ni] = __builtin_amdgcn_mfma_f32_16x16x32_f16(
                af[i][ks], bf[ni][ks], acc[2 * q + i][ni], 0, 0, 0);
      __builtin_amdgcn_s_setprio(0);
      if (q == 3 && T + 1 < NT) {
        if (T + 2 < NT) asm volatile("s_waitcnt vmcnt(3)" ::: "memory");
        else            asm volatile("s_waitcnt vmcnt(0)" ::: "memory");
      }
      __builtin_amdgcn_s_barrier();
    }
  }

  // scatter epilogue; V written TRANSPOSED (f16x4 along s)
#pragma unroll
  for (int mi = 0; mi < 8; ++mi) {
    int m0 = mb * 256 + wr * 128 + mi * 16 + 4 * g;
    int b = m0 >> 11, s0 = m0 & (NS - 1);
#pragma unroll
    for (int ni = 0; ni < 3; ++ni) {
      int n = nb * 192 + wc * 48 + ni * 16 + l15;
      if (n < 2048) {
        int h = n >> 7, d = n & 127;
        f16* qp = q_out + (((size_t)(b * N_H + h)) * NS + s0) * N_HD + d;
#pragma unroll
        for (int r = 0; r < 4; ++r) qp[r * N_HD] = (f16)acc[mi][ni][r];
      } else if (n < 2560) {
        int n2 = n - 2048, kvh = n2 >> 7, d = n2 & 127;
        f16* kp = k_out + (((size_t)(b * N_KV + kvh)) * NS + s0) * N_HD + d;
#pragma unroll
        for (int r = 0; r < 4; ++r) kp[r * N_HD] = (f16)acc[mi][ni][r];
      } else {
        int n3 = n - 2560, kvh = n3 >> 7, d = n3 & 127;
        f16x4 o4 = {(f16)acc[mi][ni][0], (f16)acc[mi][ni][1],
                    (f16)acc[mi][ni][2], (f16)acc[mi][ni][3]};
        *reinterpret_cast<f16x4*>(
            vt_out + (((size_t)(b * N_KV + kvh)) * N_HD + d) * NS + s0) = o4;
      }
    }
  }
}

// ---------------- outproj GEMM: 128x256 x BK=64, grid 256 = 1/CU, 2-phase ----------------
// 8 waves (2M x 4N; wave 64x64). 2 LDS buffers 48KB. q0 stages A(T+1)
// (opposite buffer); q1 stages B(T+2) (same buffer B-region, safe after q0's
// closing barrier). Counted vmcnt(4) at END of tile, before its closing
// barrier (cross-wave safe discipline).
__global__ __launch_bounds__(512, 2) void gemm_out(
    const f16* __restrict__ A, const f16* __restrict__ Bm,
    float* __restrict__ f_out, const float* __restrict__ bias) {
  constexpr int K = 2048;
  constexpr int NT = 32;
  __shared__ f16 lds[2][24576];
  const int t = threadIdx.x;
  const int l = t & 63, w = t >> 6;
  const int g = l >> 4, l15 = l & 15;
  const int wr = w >> 2, wc = w & 3;
  const int orig = blockIdx.x;
  const int x = orig & 7, loc = orig >> 3;   // loc 0..31
  const int mb = (x & 3) * 8 + (loc & 7);
  const int nb = (x >> 2) * 4 + (loc >> 3);
  const f16* Ab = A + (size_t)(mb * 128) * K;
  const f16* Bb = Bm + (size_t)(nb * 256) * K;

  const int rr = ((t >> 5) << 3) | (t & 7);
  const int cc = (t >> 3) & 3;
  const int dstw = w * 512;

  auto stageA = [&](int tile, int h) {
    gload16(&lds[tile & 1][h * 4096 + dstw],
            Ab + (size_t)rr * K + tile * 64 + h * 32 + cc * 8);
  };
  auto stageB = [&](int tile, int j) {  // j = h*2 + gi
    int h = j >> 1, gi = j & 1;
    gload16(&lds[tile & 1][8192 + h * 8192 + gi * 4096 + dstw],
            Bb + (size_t)(gi * 128 + rr) * K + tile * 64 + h * 32 + cc * 8);
  };

  const int fragoff = ((l15 >> 3) << 8) + (g << 6) + ((l15 & 7) << 3);
  f32x4 acc[4][4] = {};

  // prologue: tile0 all + tile1 B; drain all but tile1's 4 B, then barrier
  stageA(0, 0); stageA(0, 1);
#pragma unroll
  for (int j = 0; j < 4; ++j) stageB(0, j);
#pragma unroll
  for (int j = 0; j < 4; ++j) stageB(1, j);
  asm volatile("s_waitcnt vmcnt(4)" ::: "memory");
  __builtin_amdgcn_s_barrier();

  f16x8 bf[4][2];
  for (int T = 0; T < NT; ++T) {
    const f16* buf = lds[T & 1];
#pragma unroll
    for (int q = 0; q < 2; ++q) {
      f16x8 af[2][2];
#pragma unroll
      for (int i = 0; i < 2; ++i)
#pragma unroll
        for (int ks = 0; ks < 2; ++ks)
          af[i][ks] = *reinterpret_cast<const f16x8*>(
              buf + ks * 4096 + (wr * 64 + (2 * q + i) * 16) * 32 + fragoff);
      if (q == 0) {
#pragma unroll
        for (int ni = 0; ni < 4; ++ni)
#pragma unroll
          for (int ks = 0; ks < 2; ++ks)
            bf[ni][ks] = *reinterpret_cast<const f16x8*>(
                buf + 8192 + ks * 8192 + (wc * 64 + ni * 16) * 32 + fragoff);
      }
      if (q == 0) {
        if (T + 1 < NT) { stageA(T + 1, 0); stageA(T + 1, 1); }
      } else {
        if (T + 2 < NT) { stageB(T + 2, 0); stageB(T + 2, 1); stageB(T + 2, 2); stageB(T + 2, 3); }
      }
      __builtin_amdgcn_s_barrier();
      asm volatile("s_waitcnt lgkmcnt(0)" ::: "memory");
      __builtin_amdgcn_sched_barrier(0);
      __builtin_amdgcn_s_setprio(1);
#pragma unroll
      for (int i = 0; i < 2; ++i)
#pragma unroll
        for (int ni = 0; ni < 4; ++ni)
#pragma unroll
          for (int ks = 0; ks < 2; ++ks)
            acc[2 * q + i][ni] = __builtin_amdgcn_mfma_f32_16x16x32_f16(
                af[i][ks], bf[ni][ks], acc[2 * q + i][ni], 0, 0, 0);
      __builtin_amdgcn_s_setprio(0);
      if (q == 1 && T + 1 < NT) {
        if (T + 2 < NT) asm volatile("s_waitcnt vmcnt(4)" ::: "memory");
        else            asm volatile("s_waitcnt vmcnt(0)" ::: "memory");
      }
      __builtin_amdgcn_s_barrier();
    }
  }

#pragma unroll
  for (int mi = 0; mi < 4; ++mi) {
    int m0 = mb * 128 + wr * 64 + mi * 16 + 4 * g;
#pragma unroll
    for (int ni = 0; ni < 4; ++ni) {
      int n = nb * 256 + wc * 64 + ni * 16 + l15;
#pragma unroll
      for (int r = 0; r < 4; ++r)
        f_out[(size_t)(m0 + r) * NHID + n] = acc[mi][ni][r] + bias[n];
    }
  }
}

// ---------------- causal GQA flash attention (R5/R9 structure, known-good) ----------------
// Paired q-tiles {pi, 31-pi} share one K/V staging (uniform 33 units/block);
// K,V double-buffered in LDS, stage(kt+1) before compute(kt); exp2-domain
// softmax (log2e folded into Q); row-sum via ones-MFMA; per-wave swizzled
// P relayout. 256 threads, LDS 73728 B -> 2 blocks/CU. XCD swizzle keeps each
// XCD's K/V (1MB) L2-resident (FETCH 37.9 -> 12.4 MB measured).
__device__ __forceinline__ void stage_kv(const f16* __restrict__ Kp,
                                         const f16* __restrict__ Vp,
                                         f16* Kl, f16* Vl, int kt, int w, int l) {
#pragma unroll
  for (int it = 0; it < 4; ++it) {
    int cb = (it * 4 + w) * 64;
    int c = cb + l;
    int krow = c >> 4, pch = c & 15;
    int sch = (pch & 8) | ((pch ^ krow) & 7);
    gload16(Kl + cb * 8, Kp + (size_t)(kt * 64 + krow) * N_HD + sch * 8);
  }
#pragma unroll
  for (int it = 0; it < 4; ++it) {
    int cb = (it * 4 + w) * 64;
    int c = cb + l;
    int drow = c >> 3, pch = c & 7;
    int sch = (pch ^ drow) & 7;
    gload16(Vl + cb * 8, Vp + (size_t)drow * NS + kt * 64 + sch * 8);
  }
}

__device__ __forceinline__ void attn_step(
    const f16x8* qf, f32x4* oacc, float* mrow, float* lrow, int q0, int kt,
    const f16* Kl, const f16* Vl, f16* Pw, int g, int l15, bool diag) {
  // S = Q K^T (Q pre-scaled by log2e): acc D[q=4g+r][kpos=l15+16nt]
  f32x4 sacc[4];
#pragma unroll
  for (int nt = 0; nt < 4; ++nt) {
    f32x4 z = {0.f, 0.f, 0.f, 0.f};
#pragma unroll
    for (int ks = 0; ks < 4; ++ks) {
      int kr = nt * 16 + l15;
      int ch = ks * 4 + g;
      int sw = (ch & 8) | ((ch ^ kr) & 7);
      f16x8 kf = *reinterpret_cast<const f16x8*>(Kl + kr * 128 + sw * 8);
      z = __builtin_amdgcn_mfma_f32_16x16x32_f16(qf[ks], kf, z, 0, 0, 0);
    }
    sacc[nt] = z;
  }

  // causal mask + wave-parallel max; exp2; scale old state
  float p[4][4];
#pragma unroll
  for (int r = 0; r < 4; ++r) {
    int qg = q0 + r;
    float m = -3.0e38f;
#pragma unroll
    for (int nt = 0; nt < 4; ++nt) {
      float sv = sacc[nt][r];
      if (diag) {
        int kg = kt * 64 + nt * 16 + l15;
        if (kg > qg) sv = -3.0e38f;
      }
      p[nt][r] = sv;
      m = fmaxf(m, sv);
    }
#pragma unroll
    for (int off = 8; off >= 1; off >>= 1) m = fmaxf(m, __shfl_xor(m, off));
    float m2 = fmaxf(mrow[r], m);
    float alpha = __builtin_amdgcn_exp2f(mrow[r] - m2);
    mrow[r] = m2;
    lrow[r] *= alpha;
#pragma unroll
    for (int nt = 0; nt < 4; ++nt)
      p[nt][r] = __builtin_amdgcn_exp2f(p[nt][r] - m2);
#pragma unroll
    for (int dt = 0; dt < 8; ++dt) oacc[dt][r] *= alpha;
  }

  // P -> per-wave LDS (swizzled), then read back as A-op fragments
#pragma unroll
  for (int nt = 0; nt < 4; ++nt)
#pragma unroll
    for (int r = 0; r < 4; ++r) {
      int ql = 4 * g + r;
      int kp = nt * 16 + l15;
      int ch = kp >> 3;
      int idx = ql * 64 + (ch ^ (ql & 7)) * 8 + (kp & 7);
      Pw[idx] = (f16)p[nt][r];
    }
  asm volatile("s_waitcnt lgkmcnt(0)" ::: "memory");
  __builtin_amdgcn_sched_barrier(0);

  f16x8 pa[2];
#pragma unroll
  for (int ks2 = 0; ks2 < 2; ++ks2) {
    int ch = ks2 * 4 + g;
    pa[ks2] = *reinterpret_cast<const f16x8*>(&Pw[l15 * 64 + (ch ^ (l15 & 7)) * 8]);
  }
  // row-sum via ones-MFMA (all lanes get Sum_k P[row,k] in lacc[r])
  const f16x8 ones = {(f16)1.f, (f16)1.f, (f16)1.f, (f16)1.f,
                      (f16)1.f, (f16)1.f, (f16)1.f, (f16)1.f};
  f32x4 lacc = {0.f, 0.f, 0.f, 0.f};
#pragma unroll
  for (int ks2 = 0; ks2 < 2; ++ks2)
    lacc = __builtin_amdgcn_mfma_f32_16x16x32_f16(pa[ks2], ones, lacc, 0, 0, 0);
  // O += P V : B-op = V[k][d] from Vl[d][k]
#pragma unroll
  for (int dt = 0; dt < 8; ++dt)
#pragma unroll
    for (int ks2 = 0; ks2 < 2; ++ks2) {
      int d = dt * 16 + l15;
      int ch = ks2 * 4 + g;
      f16x8 vf = *reinterpret_cast<const f16x8*>(Vl + d * 64 + (ch ^ (d & 7)) * 8);
      oacc[dt] = __builtin_amdgcn_mfma_f32_16x16x32_f16(pa[ks2], vf, oacc[dt], 0, 0, 0);
    }
#pragma unroll
  for (int r = 0; r < 4; ++r) lrow[r] += lacc[r];
}

__global__ __launch_bounds__(256, 2) void attn_kernel(
    const f16* __restrict__ Q, const f16* __restrict__ K,
    const f16* __restrict__ Vt, f16* __restrict__ O) {
  __shared__ f16 Klds[2][64 * 128];
  __shared__ f16 Vlds[2][128 * 64];
  __shared__ f16 Plds[4][16 * 64];
  const int t = threadIdx.x, l = t & 63, w = t >> 6;
  const int g = l >> 4, l15 = l & 15;
  // XCD swizzle: XCD x owns (b,kvh) group so K/V stays L2-resident
  const int orig = blockIdx.x;               // 0..511
  const int x = orig & 7, loc = orig >> 3;   // loc 0..63
  const int b = x >> 2, kvh = x & 3;
  const int h = kvh * 4 + (loc & 3);
  const int pi = loc >> 2;                   // 0..15
  const int qtA = pi, qtB = 31 - pi;
  const f16* Qp = Q + ((size_t)(b * N_H + h)) * NS * N_HD;
  const f16* Kp = K + ((size_t)(b * N_KV + kvh)) * NS * N_HD;
  const f16* Vp = Vt + ((size_t)(b * N_KV + kvh)) * N_HD * NS;

  const f16 l2e = (f16)1.44269504f;
  f16x8 qfA[4], qfB[4];
  const int qrA = qtA * 64 + w * 16 + l15;
  const int qrB = qtB * 64 + w * 16 + l15;
#pragma unroll
  for (int ks = 0; ks < 4; ++ks) {
    qfA[ks] = *reinterpret_cast<const f16x8*>(Qp + (size_t)qrA * N_HD + ks * 32 + g * 8);
    qfB[ks] = *reinterpret_cast<const f16x8*>(Qp + (size_t)qrB * N_HD + ks * 32 + g * 8);
#pragma unroll
    for (int j = 0; j < 8; ++j) { qfA[ks][j] *= l2e; qfB[ks][j] *= l2e; }
  }

  f32x4 oA[8] = {}, oB[8] = {};
  float mA[4], lAr[4], mB[4], lBr[4];
#pragma unroll
  for (int r = 0; r < 4; ++r) {
    mA[r] = -3.0e38f; lAr[r] = 0.f;
    mB[r] = -3.0e38f; lBr[r] = 0.f;
  }
  const int q0A = qtA * 64 + w * 16 + 4 * g;
  const int q0B = qtB * 64 + w * 16 + 4 * g;

  const int nkt = qtB + 1;
  stage_kv(Kp, Vp, Klds[0], Vlds[0], 0, w, l);
  asm volatile("s_waitcnt vmcnt(0)" ::: "memory");
  __syncthreads();
  int cur = 0;
  for (int kt = 0; kt < nkt; ++kt) {
    if (kt + 1 < nkt)
      stage_kv(Kp, Vp, Klds[cur ^ 1], Vlds[cur ^ 1], kt + 1, w, l);
    attn_step(qfB, oB, mB, lBr, q0B, kt, Klds[cur], Vlds[cur], Plds[w], g, l15, kt == qtB);
    if (kt <= qtA)
      attn_step(qfA, oA, mA, lAr, q0A, kt, Klds[cur], Vlds[cur], Plds[w], g, l15, kt == qtA);
    asm volatile("s_waitcnt vmcnt(0)" ::: "memory");
    __syncthreads();
    cur ^= 1;
  }

  // normalize + write attn_out [B*S][NH*HD] fp16
#pragma unroll
  for (int r = 0; r < 4; ++r) {
    float invB = 1.0f / lBr[r];
    f16* orowB = O + (size_t)(b * NS + q0B + r) * NHID + h * N_HD;
#pragma unroll
    for (int dt = 0; dt < 8; ++dt) orowB[dt * 16 + l15] = (f16)(oB[dt][r] * invB);
    float invA = 1.0f / lAr[r];
    f16* orowA = O + (size_t)(b * NS + q0A + r) * NHID + h * N_HD;
#pragma unroll
    for (int dt = 0; dt < 8; ++dt) orowA[dt * 16 + l15] = (f16)(oA[dt][r] * invA);
  }
}

extern "C" void kernel_launch(void* const* d_in, const int* in_sizes, int n_in,
                              void* d_out, int out_size, void* d_ws, size_t ws_size,
                              hipStream_t stream) {
  const float* hs = (const float*)d_in[0];
  const float* Wq = (const float*)d_in[1];
  const float* Wk = (const float*)d_in[2];
  const float* Wv = (const float*)d_in[3];
  const float* Wo = (const float*)d_in[4];
  const float* bo = (const float*)d_in[5];
  float* out = (float*)d_out;

  char* ws = (char*)d_ws;
  f16* Xh   = (f16*)(ws);
  f16* Wqkv = (f16*)(ws + 16777216);
  f16* Woh  = (f16*)(ws + 29360128);
  f16* Qb   = (f16*)(ws + 37748736);
  f16* Kb   = (f16*)(ws + 54525952);
  f16* Vtb  = (f16*)(ws + 62914560);
  f16* Ob   = Xh;  // X dead after QKV GEMM; reuse for attention output

  cvt_all<<<18432, 256, 0, stream>>>(hs, Wq, Wk, Wv, Wo, Xh, Wqkv, Woh);
  gemm_qkv<<<256, 512, 0, stream>>>(Xh, Wqkv, Qb, Kb, Vtb);
  attn_kernel<<<512, 256, 0, stream>>>(Qb, Kb, Vtb, Ob);
  gemm_out<<<256, 512, 0, stream>>>(Ob, Woh, out, bo);
}